// Round 1
// baseline (345.663 us; speedup 1.0000x reference)
//
#include <hip/hip_runtime.h>
#include <cstdint>

#define B 32
#define L 512
#define T 2048
#define M 80
#define KDIM 160

#define NEG_INF (-1e30f)
#define LOG_2PI 1.8378770664093453f

// robust to harness passing lengths as int32 or int64 (values are small positive;
// if int64, word[1] == high word of elem0 == 0; if int32, word[1] in [64,2048] != 0)
__device__ __forceinline__ int get_len(const int* __restrict__ p, int b) {
  return (p[1] == 0) ? p[2 * b] : p[b];
}

// ---------------- prep: Wmat[b][k][l], bias[b][l] ----------------
// k in [0,80):  W = -0.5*inv_var   (pairs with x^2)
// k in [80,160): W = mu*inv_var    (pairs with x)
// bias = -0.5*sum(mu^2*inv_var) - (0.5*M*log(2pi) + 0.5*sum(log_sigma))
__global__ __launch_bounds__(256) void prep_kernel(const float* __restrict__ mu_sigma,
                                                   float* __restrict__ Wmat,
                                                   float* __restrict__ biasv) {
  int gid = blockIdx.x * 256 + threadIdx.x;  // b*L + l
  if (gid >= B * L) return;
  int b = gid >> 9;
  int l = gid & (L - 1);
  const float* row = mu_sigma + (size_t)gid * (2 * M);
  float* wb = Wmat + (size_t)b * KDIM * L + l;
  float acc_a = 0.f, acc_ls = 0.f;
#pragma unroll 4
  for (int m = 0; m < M; ++m) {
    float mu = row[m];
    float ls = row[M + m];
    float iv = expf(-2.f * ls);
    acc_a += mu * mu * iv;
    acc_ls += ls;
    wb[(size_t)m * L] = -0.5f * iv;
    wb[(size_t)(M + m) * L] = mu * iv;
  }
  biasv[gid] = -0.5f * acc_a - (0.5f * (float)M * LOG_2PI + 0.5f * acc_ls);
}

// ---------------- gemm: logpT[b][t][l] = bias[l] + sum_k X[k][t]*W[k][l] ----------------
#define LT 64
#define LL 64
#define KC 40
__global__ __launch_bounds__(256) void gemm_logp(const float* __restrict__ x,
                                                 const float* __restrict__ Wmat,
                                                 const float* __restrict__ biasv,
                                                 const int* __restrict__ mel_len,
                                                 const int* __restrict__ text_len,
                                                 float* __restrict__ logpT,
                                                 int t_begin, int tc) {
  int b = blockIdx.z;
  int t0 = t_begin + blockIdx.x * LT;
  int l0 = blockIdx.y * LL;
  if (t0 >= get_len(mel_len, b)) return;   // rows never read by the scan
  if (l0 >= get_len(text_len, b)) return;  // cols never reachable / never read

  __shared__ float Xs[KC][LT];
  __shared__ float Ws[KC][LL];
  int tid = threadIdx.x;
  int tx = tid & 15;   // t quad
  int ly = tid >> 4;   // l quad

  float acc[4][4];
#pragma unroll
  for (int i = 0; i < 4; ++i)
#pragma unroll
    for (int j = 0; j < 4; ++j) acc[i][j] = 0.f;

  for (int kc = 0; kc < KDIM; kc += KC) {
    bool sq = (kc < M);  // KC=40 divides 80, so the whole chunk is one regime
#pragma unroll
    for (int p = 0; p < (KC * LT) / 256; ++p) {  // 10 passes
      int idx = p * 256 + tid;
      int kk = idx >> 6;
      int cc = idx & 63;
      int k = kc + kk;
      int m = sq ? k : (k - M);
      float xv = x[((size_t)b * M + m) * T + t0 + cc];
      Xs[kk][cc] = sq ? xv * xv : xv;
      Ws[kk][cc] = Wmat[((size_t)b * KDIM + k) * L + l0 + cc];
    }
    __syncthreads();
#pragma unroll 8
    for (int k = 0; k < KC; ++k) {
      float xa[4], wa[4];
#pragma unroll
      for (int i = 0; i < 4; ++i) xa[i] = Xs[k][tx * 4 + i];
#pragma unroll
      for (int j = 0; j < 4; ++j) wa[j] = Ws[k][ly * 4 + j];
#pragma unroll
      for (int i = 0; i < 4; ++i)
#pragma unroll
        for (int j = 0; j < 4; ++j) acc[i][j] += xa[i] * wa[j];
    }
    __syncthreads();
  }

  float bb[4];
#pragma unroll
  for (int j = 0; j < 4; ++j) bb[j] = biasv[b * L + l0 + ly * 4 + j];
#pragma unroll
  for (int i = 0; i < 4; ++i) {
    int t = t0 + tx * 4 + i;
    float4 v;
    v.x = acc[i][0] + bb[0];
    v.y = acc[i][1] + bb[1];
    v.z = acc[i][2] + bb[2];
    v.w = acc[i][3] + bb[3];
    *(float4*)(logpT + ((size_t)b * tc + (t - t_begin)) * L + l0 + ly * 4) = v;
  }
}

// ---------------- scan: one wave per batch, max-plus (Viterbi) recursion ----------------
// lane owns l = lane*8 + j (j=0..7); only j=0 needs the neighbor lane's j=7.
#define SB 16  // t-rows per staged LDS batch
__global__ __launch_bounds__(64) void scan_kernel(const float* __restrict__ logpT,
                                                  const int* __restrict__ mel_len,
                                                  const int* __restrict__ text_len,
                                                  float* __restrict__ carry_ws,
                                                  float* __restrict__ la_ws,
                                                  int t_begin, int tc) {
  __shared__ float lds[2][SB][L];
  int b = blockIdx.x;
  int lane = threadIdx.x;
  int ml = get_len(mel_len, b);
  int tl = get_len(text_len, b);
  const float* base = logpT + (size_t)b * tc * L;
  float* cws = carry_ws + b * L + lane * 8;

  float c[8];
  int tstart;
  if (t_begin == 0) {
#pragma unroll
    for (int j = 0; j < 8; ++j) c[j] = NEG_INF;
    if (lane == 0) c[0] = base[0];  // logp[b,0,0]
    tstart = 1;
  } else {
    float4 v0 = *(const float4*)(cws);
    float4 v1 = *(const float4*)(cws + 4);
    c[0] = v0.x; c[1] = v0.y; c[2] = v0.z; c[3] = v0.w;
    c[4] = v1.x; c[5] = v1.y; c[6] = v1.z; c[7] = v1.w;
    tstart = t_begin;
  }

  int tstop = min(t_begin + tc, ml);

  auto stage = [&](int buf, int tb) {
    const float* src = base + (size_t)(tb - t_begin) * L;
#pragma unroll
    for (int i = 0; i < (SB * L) / 256; ++i) {  // 32 x 1KB
      __builtin_amdgcn_global_load_lds(
          (const __attribute__((address_space(1))) void*)(src + i * 256 + lane * 4),
          (__attribute__((address_space(3))) void*)(&lds[buf][0][0] + i * 256),
          16, 0, 0);
    }
  };

  if (t_begin < tstop) {
    int cur = 0;
    stage(0, t_begin);
    asm volatile("s_waitcnt vmcnt(0)" ::: "memory");
    for (int tb = t_begin; tb < tstop; tb += SB) {
      if (tb + SB < tstop) stage(cur ^ 1, tb + SB);
      int e = min(tb + SB, tstop);
      for (int t = max(tb, tstart); t < e; ++t) {
        const float* r = &lds[cur][t - tb][lane * 8];
        float4 l0 = *(const float4*)(r);
        float4 l1 = *(const float4*)(r + 4);
        float sh = __shfl_up(c[7], 1);
        float p0 = (lane == 0) ? NEG_INF : sh;
        c[7] = fmaxf(c[7], c[6]) + l1.w;
        c[6] = fmaxf(c[6], c[5]) + l1.z;
        c[5] = fmaxf(c[5], c[4]) + l1.y;
        c[4] = fmaxf(c[4], c[3]) + l1.x;
        c[3] = fmaxf(c[3], c[2]) + l0.w;
        c[2] = fmaxf(c[2], c[1]) + l0.z;
        c[1] = fmaxf(c[1], c[0]) + l0.y;
        c[0] = fmaxf(c[0], p0) + l0.x;
      }
      asm volatile("s_waitcnt vmcnt(0)" ::: "memory");
      cur ^= 1;
    }
  }

  // persist carry for next chunk
  *(float4*)(cws) = make_float4(c[0], c[1], c[2], c[3]);
  *(float4*)(cws + 4) = make_float4(c[4], c[5], c[6], c[7]);

  if (t_begin + tc >= T) {  // last chunk: extract la[b] = alpha[ml-1][tl-1]
    int li = tl - 1;
    float csel = NEG_INF;
#pragma unroll
    for (int j = 0; j < 8; ++j)
      if ((li & 7) == j) csel = c[j];
    float lav = __shfl(csel, li >> 3);
    if (lane == 0) la_ws[b] = lav;
  }
}

__global__ __launch_bounds__(64) void reduce_kernel(const float* __restrict__ la_ws,
                                                    float* __restrict__ out) {
  int lane = threadIdx.x;
  float v = (lane < B) ? la_ws[lane] : 0.f;
#pragma unroll
  for (int s = 32; s > 0; s >>= 1) v += __shfl_down(v, s);
  if (lane == 0) out[0] = -v * (1.0f / (float)B);
}

extern "C" void kernel_launch(void* const* d_in, const int* in_sizes, int n_in,
                              void* d_out, int out_size, void* d_ws, size_t ws_size,
                              hipStream_t stream) {
  const float* mu_sigma = (const float*)d_in[0];
  const float* melspec  = (const float*)d_in[1];
  const int*   text_len = (const int*)d_in[2];
  const int*   mel_len  = (const int*)d_in[3];
  float* out = (float*)d_out;

  char* ws = (char*)d_ws;
  size_t off = 0;
  float* Wmat = (float*)(ws + off);      off += (size_t)B * KDIM * L * 4;  // 10.5 MB
  float* biasv = (float*)(ws + off);     off += (size_t)B * L * 4;
  float* carry_ws = (float*)(ws + off);  off += (size_t)B * L * 4;
  float* la_ws = (float*)(ws + off);     off += 256;
  float* logpT = (float*)(ws + off);
  size_t avail = (ws_size > off) ? (ws_size - off) : 0;
  size_t per_t = (size_t)B * L * 4;  // bytes per t-slice across all b
  long long tcl = (long long)(avail / per_t);
  int Tc = (tcl > T) ? T : (int)tcl;
  Tc &= ~63;
  if (Tc < 64) return;  // insufficient workspace (not expected)

  prep_kernel<<<dim3((B * L + 255) / 256), 256, 0, stream>>>(mu_sigma, Wmat, biasv);

  for (int t_begin = 0; t_begin < T; t_begin += Tc) {
    int tc = (T - t_begin < Tc) ? (T - t_begin) : Tc;
    dim3 grid(tc / LT, L / LL, B);
    gemm_logp<<<grid, 256, 0, stream>>>(melspec, Wmat, biasv, mel_len, text_len,
                                        logpT, t_begin, tc);
    scan_kernel<<<dim3(B), 64, 0, stream>>>(logpT, mel_len, text_len, carry_ws,
                                            la_ws, t_begin, tc);
  }
  reduce_kernel<<<1, 64, 0, stream>>>(la_ws, out);
}